// Round 2
// baseline (168.634 us; speedup 1.0000x reference)
//
#include <hip/hip_runtime.h>
#include <hip/hip_bf16.h>

// Problem constants (B=2, T=2048, C=1024, H=16, G=4, hd=64, KV=256, WINDOW=256)
#define TT 2048
#define CC 1024
#define KVD 256
#define QKVD 1536

typedef __bf16 bf16x8 __attribute__((ext_vector_type(8)));
typedef float f32x4 __attribute__((ext_vector_type(4)));

// async global->LDS, 16B per lane. LDS dest is wave-uniform base + lane*16 (HW rule).
__device__ __forceinline__ void gload_lds16(const __hip_bfloat16* g, __hip_bfloat16* l) {
  __builtin_amdgcn_global_load_lds(
      (const __attribute__((address_space(1))) unsigned int*)g,
      (__attribute__((address_space(3))) unsigned int*)l, 16, 0, 0);
}

// ---------------- merged prep: x->bf16 convert + weight packs + bias ----------------
// 1D grid: [0,4096) convert x; [4096,4480) pack wqkvT; [4480,4736) pack woT; [4736] bias.

__global__ __launch_bounds__(256) void k_prep(const float* __restrict__ x,
                                              const float* __restrict__ Wq,
                                              const float* __restrict__ Wk,
                                              const float* __restrict__ Wv,
                                              const float* __restrict__ Wo,
                                              const float* __restrict__ bq,
                                              const float* __restrict__ bk,
                                              const float* __restrict__ bv,
                                              __hip_bfloat16* __restrict__ xbf,
                                              __hip_bfloat16* __restrict__ wqkvT,
                                              __hip_bfloat16* __restrict__ woT,
                                              float* __restrict__ bqkv) {
  const int bxid = blockIdx.x;
  if (bxid < 4096) {
    size_t idx = ((size_t)bxid * 256 + threadIdx.x) * 4;
    float4 v = *(const float4*)(x + idx);
    xbf[idx + 0] = __float2bfloat16(v.x);
    xbf[idx + 1] = __float2bfloat16(v.y);
    xbf[idx + 2] = __float2bfloat16(v.z);
    xbf[idx + 3] = __float2bfloat16(v.w);
    return;
  }
  if (bxid == 4736) {
    for (int i = threadIdx.x; i < 1536; i += 256) {
      float v;
      if (i < 1024)      v = bq[i];
      else if (i < 1280) v = bk[i - 1024];
      else               v = bv[i - 1280];
      bqkv[i] = v;
    }
    return;
  }
  // weight pack via LDS tile transpose, coalesced both sides
  __shared__ float tile[64][65];
  const float* src;
  int ncols, k0, n0;
  __hip_bfloat16* dst;
  if (bxid < 4480) {
    const int idx = bxid - 4096;          // 384 tiles: 16 k x 24 n
    k0 = (idx & 15) * 64;
    n0 = (idx >> 4) * 64;
    dst = wqkvT;
    if (n0 < 1024)      { src = Wq; ncols = 1024; }
    else if (n0 < 1280) { src = Wk - 1024; ncols = 256; }
    else                { src = Wv - 1280; ncols = 256; }
  } else {
    const int idx = bxid - 4480;          // 256 tiles: 16 k x 16 n
    k0 = (idx & 15) * 64;
    n0 = (idx >> 4) * 64;
    dst = woT; src = Wo; ncols = 1024;
  }
  const int rw = threadIdx.x >> 6;
  const int cl = threadIdx.x & 63;
#pragma unroll
  for (int i = 0; i < 16; ++i) {
    const int kr = rw + i * 4;
    tile[kr][cl] = src[(size_t)(k0 + kr) * ncols + n0 + cl];
  }
  __syncthreads();
#pragma unroll
  for (int i = 0; i < 16; ++i) {
    const int nr = rw + i * 4;
    dst[(size_t)(n0 + nr) * 1024 + k0 + cl] = __float2bfloat16(tile[cl][nr]);
  }
}

// ---------------- gemm1: QKV projection, m97-style 128x128 tile, BK=64 -------------
// [4096 x 1024] * [1024 x 1536]^T-packed. Single-buffer 2-barrier K-loop (m97), 128
// MFMA per block-barrier, MFMA:ds_read=2:1, XOR-swizzled conflict-free LDS.
// V columns (n>=1280) written transposed into vtg[(b*4+g)*64 + d][t].
// grid (1536/128, 4096/128) = (12, 32).

__global__ __launch_bounds__(256, 3) void k_gemm1(const __hip_bfloat16* __restrict__ A,
                                                  const __hip_bfloat16* __restrict__ BT,
                                                  const float* __restrict__ bias,
                                                  __hip_bfloat16* __restrict__ C,
                                                  __hip_bfloat16* __restrict__ vtg) {
  __shared__ __hip_bfloat16 As[128][64];   // 16 KB
  __shared__ __hip_bfloat16 Bs[128][64];   // 16 KB

  const int tid  = threadIdx.x;
  const int m0   = blockIdx.y * 128;
  const int n0   = blockIdx.x * 128;
  const int w    = tid >> 6;
  const int lane = tid & 63;
  const int quad = lane >> 4;
  const int l16  = lane & 15;
  const int wm   = (w >> 1) * 64;
  const int wn   = (w & 1) * 64;

  const int dl_r = lane >> 3;               // 0..7
  const int dl_c = (lane & 7) ^ dl_r;       // swizzled global 16B chunk

  const __hip_bfloat16* gA = A + (size_t)(m0 + w * 32 + dl_r) * 1024 + dl_c * 8;
  const __hip_bfloat16* gB = BT + (size_t)(n0 + w * 32 + dl_r) * 1024 + dl_c * 8;

  f32x4 acc[4][4] = {};

  for (int kt = 0; kt < 16; ++kt) {
    const int k0 = kt << 6;
#pragma unroll
    for (int rr = 0; rr < 4; ++rr) {
      gload_lds16(gA + k0 + (size_t)(rr * 8) * 1024, &As[w * 32 + rr * 8][0]);
      gload_lds16(gB + k0 + (size_t)(rr * 8) * 1024, &Bs[w * 32 + rr * 8][0]);
    }
    __syncthreads();  // drain DMA

#pragma unroll
    for (int ks = 0; ks < 2; ++ks) {
      const int cb = (ks << 2) + quad;
      bf16x8 fa[4], fb[4];
#pragma unroll
      for (int i = 0; i < 4; ++i)
        fa[i] = *(const bf16x8*)&As[wm + i * 16 + l16][(cb ^ (l16 & 7)) << 3];
#pragma unroll
      for (int j = 0; j < 4; ++j)
        fb[j] = *(const bf16x8*)&Bs[wn + j * 16 + l16][(cb ^ (l16 & 7)) << 3];
#pragma unroll
      for (int i = 0; i < 4; ++i)
#pragma unroll
        for (int j = 0; j < 4; ++j)
          acc[i][j] = __builtin_amdgcn_mfma_f32_16x16x32_bf16(fa[i], fb[j], acc[i][j], 0, 0, 0);
    }
    __syncthreads();  // all reads done before next overwrite
  }

  // epilogue: C/D layout col=lane&15, row=quad*4+reg. 1280 boundary is wave-uniform.
#pragma unroll
  for (int j = 0; j < 4; ++j) {
    const int gn = n0 + wn + j * 16 + l16;
    const float bias_v = bias[gn];
    if (gn >= 1280) {
      // V column: write transposed into vtg[(b*4+g)*64 + d][t]
      const int dfull = gn - 1280;
      const int gg = dfull >> 6;
      const int dd = dfull & 63;
#pragma unroll
      for (int i = 0; i < 4; ++i) {
        const int gm = m0 + wm + i * 16 + quad * 4;  // 4 consecutive tokens
        const int bb = gm >> 11;
        const int tl = gm & 2047;
        __hip_bfloat16 tmp[4];
#pragma unroll
        for (int r = 0; r < 4; ++r) tmp[r] = __float2bfloat16(acc[i][j][r] + bias_v);
        *(uint2*)(vtg + ((size_t)((bb * 4 + gg) * 64 + dd)) * TT + tl) = *(const uint2*)tmp;
      }
    } else {
#pragma unroll
      for (int i = 0; i < 4; ++i) {
        const int gmb = m0 + wm + i * 16 + quad * 4;
#pragma unroll
        for (int r = 0; r < 4; ++r)
          C[(size_t)(gmb + r) * QKVD + gn] = __float2bfloat16(acc[i][j][r] + bias_v);
      }
    }
  }
}

// ---------------- gemm2: output projection, 64x128 tile, BK=64, single-buffer ------
// [4096 x 1024] * [1024 x 1024]^T-packed -> fp32 out. grid (8, 64) = 512 blocks.

__global__ __launch_bounds__(256, 4) void k_gemm2(const __hip_bfloat16* __restrict__ A,
                                                  const __hip_bfloat16* __restrict__ BT,
                                                  const float* __restrict__ bias,
                                                  float* __restrict__ C) {
  __shared__ __hip_bfloat16 As[64][64];
  __shared__ __hip_bfloat16 Bs[128][64];

  const int tid  = threadIdx.x;
  const int m0   = blockIdx.y * 64;
  const int n0   = blockIdx.x * 128;
  const int w    = tid >> 6;
  const int lane = tid & 63;
  const int quad = lane >> 4;
  const int l16  = lane & 15;
  const int wm   = (w >> 1) * 32;
  const int wn   = (w & 1) * 64;

  const int dl_r = lane >> 3;
  const int dl_c = (lane & 7) ^ dl_r;

  const __hip_bfloat16* gA = A + (size_t)(m0 + w * 16 + dl_r) * 1024 + dl_c * 8;
  const __hip_bfloat16* gB = BT + (size_t)(n0 + w * 32 + dl_r) * 1024 + dl_c * 8;

  f32x4 acc[2][4] = {};

  for (int kt = 0; kt < 16; ++kt) {
    const int k0 = kt << 6;
    gload_lds16(gA + k0,                     &As[w * 16][0]);
    gload_lds16(gA + k0 + (size_t)8 * 1024,  &As[w * 16 + 8][0]);
    gload_lds16(gB + k0,                     &Bs[w * 32][0]);
    gload_lds16(gB + k0 + (size_t)8 * 1024,  &Bs[w * 32 + 8][0]);
    gload_lds16(gB + k0 + (size_t)16 * 1024, &Bs[w * 32 + 16][0]);
    gload_lds16(gB + k0 + (size_t)24 * 1024, &Bs[w * 32 + 24][0]);
    __syncthreads();

#pragma unroll
    for (int ks = 0; ks < 2; ++ks) {
      const int cb = (ks << 2) + quad;
      bf16x8 fa[2], fb[4];
#pragma unroll
      for (int i = 0; i < 2; ++i)
        fa[i] = *(const bf16x8*)&As[wm + i * 16 + l16][(cb ^ (l16 & 7)) << 3];
#pragma unroll
      for (int j = 0; j < 4; ++j)
        fb[j] = *(const bf16x8*)&Bs[wn + j * 16 + l16][(cb ^ (l16 & 7)) << 3];
#pragma unroll
      for (int i = 0; i < 2; ++i)
#pragma unroll
        for (int j = 0; j < 4; ++j)
          acc[i][j] = __builtin_amdgcn_mfma_f32_16x16x32_bf16(fa[i], fb[j], acc[i][j], 0, 0, 0);
    }
    __syncthreads();
  }

#pragma unroll
  for (int j = 0; j < 4; ++j) {
    const int gn = n0 + wn + j * 16 + l16;
    const float bias_v = bias[gn];
#pragma unroll
    for (int i = 0; i < 2; ++i) {
      const int gmb = m0 + wm + i * 16 + quad * 4;
#pragma unroll
      for (int r = 0; r < 4; ++r)
        C[(size_t)(gmb + r) * CC + gn] = acc[i][j][r] + bias_v;
    }
  }
}

// ---------------- MFMA flash attention v3: barrier-free, L2-direct -----------------
// K (2 MB) and V-transposed (2 MB) are L2/L3-resident; LDS staging was pure overhead
// (Common-mistake #7) and its barrier-drain made the kernel latency-bound (R0->R1
// regression evidence). v3 reads K/V fragments DIRECTLY from global per lane:
//   fk: lanes (l16,quad) read 16B at row c*64+nt*16+l16, d = ks*32+quad*8
//       -> the 4 quads of one l16 cover 64 contiguous bytes: 16 cache lines/load, 100% used.
//   fv: same structure on vtg rows (d) x contiguous t.
// No __syncthreads anywhere (Ps is per-wave; intra-wave ds ordering is automatic).
// LDS = 9.2 KB only -> occupancy is VGPR-limited; waves free-run across chunks.

__global__ __launch_bounds__(256) void k_attn(const __hip_bfloat16* __restrict__ qkv,
                                              const __hip_bfloat16* __restrict__ vtg,
                                              __hip_bfloat16* __restrict__ y) {
  __shared__ __hip_bfloat16 Ps[4][16][72];  // per-wave P tile 9.2 KB

  const int t    = threadIdx.x;
  const int w    = t >> 6;
  const int lane = t & 63;
  const int quad = lane >> 4;
  const int l16  = lane & 15;
  const int bx   = blockIdx.x;
  const int h    = blockIdx.y;
  const int b    = blockIdx.z;
  const int g    = h >> 2;  // repeat_interleave: heads 4g..4g+3 -> group g
  const int i0   = bx * 64;
  const int qrow      = i0 + w * 16 + l16;
  const int my_q_base = i0 + w * 16 + quad * 4;

  // per-lane K fragment base: row l16 of chunk, d = quad*8 (ks adds 32)
  const __hip_bfloat16* kg =
      qkv + ((size_t)(b * TT + l16)) * QKVD + 1024 + g * 64 + quad * 8;
  // per-lane V fragment base: vtg row d = l16 (jt adds 16), t-col = quad*8 (ks adds 32)
  const __hip_bfloat16* vg =
      vtg + ((size_t)((b * 4 + g) * 64 + l16)) * TT + quad * 8;

  bf16x8 fq[2];
  {
    const __hip_bfloat16* qp = qkv + ((size_t)(b * TT + qrow)) * QKVD + h * 64 + quad * 8;
    fq[0] = *(const bf16x8*)qp;
    fq[1] = *(const bf16x8*)(qp + 32);
  }

  float l_r[4] = {0.f, 0.f, 0.f, 0.f};
  f32x4 o_acc[4] = {};
  const float EC = 0.125f * 1.44269504f;  // (1/sqrt(64)) * log2(e)

  const int c_lo = bx >= 4 ? bx - 4 : 0;

  for (int c = c_lo; c <= bx; ++c) {
    const int jc = c * 64;
    const __hip_bfloat16* kgc = kg + (size_t)jc * QKVD;
    const __hip_bfloat16* vgc = vg + jc;

    // QK^T: K fragments straight from L2
    f32x4 sacc[4] = {};
    bf16x8 fk[2][4];
#pragma unroll
    for (int ks = 0; ks < 2; ++ks)
#pragma unroll
      for (int nt = 0; nt < 4; ++nt)
        fk[ks][nt] = *(const bf16x8*)(kgc + (size_t)(nt * 16) * QKVD + ks * 32);
    __builtin_amdgcn_s_setprio(1);
#pragma unroll
    for (int ks = 0; ks < 2; ++ks)
#pragma unroll
      for (int nt = 0; nt < 4; ++nt)
        sacc[nt] = __builtin_amdgcn_mfma_f32_16x16x32_bf16(fq[ks], fk[ks][nt], sacc[nt], 0, 0, 0);
    __builtin_amdgcn_s_setprio(0);

    // prefetch V fragments for this chunk while softmax runs
    bf16x8 fv[2][4];
#pragma unroll
    for (int ks = 0; ks < 2; ++ks)
#pragma unroll
      for (int jt = 0; jt < 4; ++jt)
        fv[ks][jt] = *(const bf16x8*)(vgc + (size_t)(jt * 16) * TT + ks * 32);

    // p = exp(s/8); mask only where needed (wave-uniform chunk classification)
    if (c == bx) {            // diagonal: key <= i
#pragma unroll
      for (int r = 0; r < 4; ++r) {
        const int gi = my_q_base + r;
#pragma unroll
        for (int nt = 0; nt < 4; ++nt) {
          const int key = jc + nt * 16 + l16;
          const float p = (key <= gi) ? exp2f(sacc[nt][r] * EC) : 0.f;
          l_r[r] += p;
          Ps[w][quad * 4 + r][nt * 16 + l16] = __float2bfloat16(p);
        }
      }
    } else if (bx >= 4 && c == c_lo) {  // window tail: key >= i - 256
#pragma unroll
      for (int r = 0; r < 4; ++r) {
        const int glo = my_q_base + r - 256;
#pragma unroll
        for (int nt = 0; nt < 4; ++nt) {
          const int key = jc + nt * 16 + l16;
          const float p = (key >= glo) ? exp2f(sacc[nt][r] * EC) : 0.f;
          l_r[r] += p;
          Ps[w][quad * 4 + r][nt * 16 + l16] = __float2bfloat16(p);
        }
      }
    } else {                  // interior: mask-free
#pragma unroll
      for (int r = 0; r < 4; ++r)
#pragma unroll
        for (int nt = 0; nt < 4; ++nt) {
          const float p = exp2f(sacc[nt][r] * EC);
          l_r[r] += p;
          Ps[w][quad * 4 + r][nt * 16 + l16] = __float2bfloat16(p);
        }
    }

    const bf16x8 fp0 = *(const bf16x8*)&Ps[w][l16][quad * 8];
    const bf16x8 fp1 = *(const bf16x8*)&Ps[w][l16][32 + quad * 8];

    __builtin_amdgcn_s_setprio(1);
#pragma unroll
    for (int ks = 0; ks < 2; ++ks)
#pragma unroll
      for (int jt = 0; jt < 4; ++jt)
        o_acc[jt] = __builtin_amdgcn_mfma_f32_16x16x32_bf16(ks == 0 ? fp0 : fp1, fv[ks][jt],
                                                            o_acc[jt], 0, 0, 0);
    __builtin_amdgcn_s_setprio(0);
  }

#pragma unroll
  for (int r = 0; r < 4; ++r) {
#pragma unroll
    for (int d = 1; d < 16; d <<= 1) l_r[r] += __shfl_xor(l_r[r], d);
    const float inv = 1.f / l_r[r];
    __hip_bfloat16* yp = y + ((size_t)(b * TT + my_q_base + r)) * CC + h * 64 + l16;
#pragma unroll
    for (int jt = 0; jt < 4; ++jt)
      yp[jt * 16] = __float2bfloat16(o_acc[jt][r] * inv);
  }
}

// ---------------- launch ----------------

extern "C" void kernel_launch(void* const* d_in, const int* in_sizes, int n_in,
                              void* d_out, int out_size, void* d_ws, size_t ws_size,
                              hipStream_t stream) {
  const float* x  = (const float*)d_in[0];
  const float* Wq = (const float*)d_in[1];
  const float* bq = (const float*)d_in[2];
  const float* Wk = (const float*)d_in[3];
  const float* bk = (const float*)d_in[4];
  const float* Wv = (const float*)d_in[5];
  const float* bv = (const float*)d_in[6];
  const float* Wo = (const float*)d_in[7];
  const float* bo = (const float*)d_in[8];
  float* out = (float*)d_out;

  char* ws = (char*)d_ws;
  const size_t M = 2 * TT;  // 4096
  __hip_bfloat16* xbf   = (__hip_bfloat16*)(ws);               // 8 MB
  __hip_bfloat16* qkv   = (__hip_bfloat16*)(ws + 8388608);     // 12 MB (V region unused)
  __hip_bfloat16* ybf   = (__hip_bfloat16*)(ws + 20971520);    // 8 MB
  __hip_bfloat16* wqkvT = (__hip_bfloat16*)(ws + 29360128);    // 3 MB
  __hip_bfloat16* woT   = (__hip_bfloat16*)(ws + 32505856);    // 2 MB
  float*          bqkv  = (float*)(ws + 34603008);             // 6 KB
  __hip_bfloat16* vtg   = (__hip_bfloat16*)(ws + 34609152);    // 2 MB

  // prep: x convert (4096) + wqkv pack (384) + wo pack (256) + bias (1)
  k_prep<<<4737, 256, 0, stream>>>(x, Wq, Wk, Wv, Wo, bq, bk, bv,
                                   xbf, wqkvT, woT, bqkv);

  // QKV projection: 128x128 tiles, grid (12, 32); V columns go transposed to vtg
  k_gemm1<<<dim3(QKVD / 128, M / 128), 256, 0, stream>>>(xbf, wqkvT, bqkv, qkv, vtg);

  // attention: 1024 blocks, barrier-free L2-direct flash
  k_attn<<<dim3(TT / 64, 16, 2), 256, 0, stream>>>(qkv, vtg, ybf);

  // output projection: 64x128 tiles, grid (8, 64) -> fp32
  k_gemm2<<<dim3(CC / 128, M / 64), 256, 0, stream>>>(ybf, woT, bo, out);
}

// Round 3
// 145.061 us; speedup vs baseline: 1.1625x; 1.1625x over previous
//
#include <hip/hip_runtime.h>
#include <hip/hip_bf16.h>

// Problem constants (B=2, T=2048, C=1024, H=16, G=4, hd=64, KV=256, WINDOW=256)
#define TT 2048
#define CC 1024
#define KVD 256
#define QKVD 1536

typedef __bf16 bf16x8 __attribute__((ext_vector_type(8)));
typedef float f32x4 __attribute__((ext_vector_type(4)));

// async global->LDS, 16B per lane. LDS dest is wave-uniform base + lane*16 (HW rule).
__device__ __forceinline__ void gload_lds16(const __hip_bfloat16* g, __hip_bfloat16* l) {
  __builtin_amdgcn_global_load_lds(
      (const __attribute__((address_space(1))) unsigned int*)g,
      (__attribute__((address_space(3))) unsigned int*)l, 16, 0, 0);
}

// ---------------- merged prep: x->bf16 convert + weight packs + bias ----------------
// 1D grid: [0,4096) convert x; [4096,4480) pack wqkvT; [4480,4736) pack woT; [4736] bias.

__global__ __launch_bounds__(256) void k_prep(const float* __restrict__ x,
                                              const float* __restrict__ Wq,
                                              const float* __restrict__ Wk,
                                              const float* __restrict__ Wv,
                                              const float* __restrict__ Wo,
                                              const float* __restrict__ bq,
                                              const float* __restrict__ bk,
                                              const float* __restrict__ bv,
                                              __hip_bfloat16* __restrict__ xbf,
                                              __hip_bfloat16* __restrict__ wqkvT,
                                              __hip_bfloat16* __restrict__ woT,
                                              float* __restrict__ bqkv) {
  const int bxid = blockIdx.x;
  if (bxid < 4096) {
    size_t idx = ((size_t)bxid * 256 + threadIdx.x) * 4;
    float4 v = *(const float4*)(x + idx);
    xbf[idx + 0] = __float2bfloat16(v.x);
    xbf[idx + 1] = __float2bfloat16(v.y);
    xbf[idx + 2] = __float2bfloat16(v.z);
    xbf[idx + 3] = __float2bfloat16(v.w);
    return;
  }
  if (bxid == 4736) {
    for (int i = threadIdx.x; i < 1536; i += 256) {
      float v;
      if (i < 1024)      v = bq[i];
      else if (i < 1280) v = bk[i - 1024];
      else               v = bv[i - 1280];
      bqkv[i] = v;
    }
    return;
  }
  // weight pack via LDS tile transpose, coalesced both sides
  __shared__ float tile[64][65];
  const float* src;
  int ncols, k0, n0;
  __hip_bfloat16* dst;
  if (bxid < 4480) {
    const int idx = bxid - 4096;          // 384 tiles: 16 k x 24 n
    k0 = (idx & 15) * 64;
    n0 = (idx >> 4) * 64;
    dst = wqkvT;
    if (n0 < 1024)      { src = Wq; ncols = 1024; }
    else if (n0 < 1280) { src = Wk - 1024; ncols = 256; }
    else                { src = Wv - 1280; ncols = 256; }
  } else {
    const int idx = bxid - 4480;          // 256 tiles: 16 k x 16 n
    k0 = (idx & 15) * 64;
    n0 = (idx >> 4) * 64;
    dst = woT; src = Wo; ncols = 1024;
  }
  const int rw = threadIdx.x >> 6;
  const int cl = threadIdx.x & 63;
#pragma unroll
  for (int i = 0; i < 16; ++i) {
    const int kr = rw + i * 4;
    tile[kr][cl] = src[(size_t)(k0 + kr) * ncols + n0 + cl];
  }
  __syncthreads();
#pragma unroll
  for (int i = 0; i < 16; ++i) {
    const int nr = rw + i * 4;
    dst[(size_t)(n0 + nr) * 1024 + k0 + cl] = __float2bfloat16(tile[cl][nr]);
  }
}

// ---------------- gemm1: QKV projection, 128x128 tile, BK=64, 8 waves -------------
// [4096 x 1024] * [1024 x 1536]^T-packed. v4: 512-thread blocks (8 waves, wave-tile
// 32x64). Grid 384 blocks was only 6 waves/CU at 4 waves/block -> latency-bound at
// the vmcnt(0) barrier drain; 8 waves/block doubles resident waves (avg 12/CU).
// Same LDS (32 KB), same XOR swizzle. V columns (n>=1280) -> vtg transposed.
// grid (1536/128, 4096/128) = (12, 32).

__global__ __launch_bounds__(512, 4) void k_gemm1(const __hip_bfloat16* __restrict__ A,
                                                  const __hip_bfloat16* __restrict__ BT,
                                                  const float* __restrict__ bias,
                                                  __hip_bfloat16* __restrict__ C,
                                                  __hip_bfloat16* __restrict__ vtg) {
  __shared__ __hip_bfloat16 As[128][64];   // 16 KB
  __shared__ __hip_bfloat16 Bs[128][64];   // 16 KB

  const int tid  = threadIdx.x;
  const int m0   = blockIdx.y * 128;
  const int n0   = blockIdx.x * 128;
  const int w    = tid >> 6;               // 0..7
  const int lane = tid & 63;
  const int quad = lane >> 4;
  const int l16  = lane & 15;
  const int wm   = (w & 3) * 32;           // 4 row-groups of 32
  const int wn   = (w >> 2) * 64;          // 2 col-groups of 64

  const int dl_r = lane >> 3;               // 0..7
  const int dl_c = (lane & 7) ^ dl_r;       // swizzled global 16B chunk

  // wave w stages A rows [w*16, w*16+16) and B rows [w*16, w*16+16)
  const __hip_bfloat16* gA = A + (size_t)(m0 + w * 16 + dl_r) * 1024 + dl_c * 8;
  const __hip_bfloat16* gB = BT + (size_t)(n0 + w * 16 + dl_r) * 1024 + dl_c * 8;

  f32x4 acc[2][4] = {};

  for (int kt = 0; kt < 16; ++kt) {
    const int k0 = kt << 6;
    gload_lds16(gA + k0,                    &As[w * 16][0]);
    gload_lds16(gA + k0 + (size_t)8 * 1024, &As[w * 16 + 8][0]);
    gload_lds16(gB + k0,                    &Bs[w * 16][0]);
    gload_lds16(gB + k0 + (size_t)8 * 1024, &Bs[w * 16 + 8][0]);
    __syncthreads();  // drain DMA

#pragma unroll
    for (int ks = 0; ks < 2; ++ks) {
      const int cb = (ks << 2) + quad;
      bf16x8 fa[2], fb[4];
#pragma unroll
      for (int i = 0; i < 2; ++i)
        fa[i] = *(const bf16x8*)&As[wm + i * 16 + l16][(cb ^ (l16 & 7)) << 3];
#pragma unroll
      for (int j = 0; j < 4; ++j)
        fb[j] = *(const bf16x8*)&Bs[wn + j * 16 + l16][(cb ^ (l16 & 7)) << 3];
#pragma unroll
      for (int i = 0; i < 2; ++i)
#pragma unroll
        for (int j = 0; j < 4; ++j)
          acc[i][j] = __builtin_amdgcn_mfma_f32_16x16x32_bf16(fa[i], fb[j], acc[i][j], 0, 0, 0);
    }
    __syncthreads();  // all reads done before next overwrite
  }

  // epilogue: C/D layout col=lane&15, row=quad*4+reg. 1280 boundary is wave-uniform.
#pragma unroll
  for (int j = 0; j < 4; ++j) {
    const int gn = n0 + wn + j * 16 + l16;
    const float bias_v = bias[gn];
    if (gn >= 1280) {
      // V column: write transposed into vtg[(b*4+g)*64 + d][t]
      const int dfull = gn - 1280;
      const int gg = dfull >> 6;
      const int dd = dfull & 63;
#pragma unroll
      for (int i = 0; i < 2; ++i) {
        const int gm = m0 + wm + i * 16 + quad * 4;  // 4 consecutive tokens
        const int bb = gm >> 11;
        const int tl = gm & 2047;
        __hip_bfloat16 tmp[4];
#pragma unroll
        for (int r = 0; r < 4; ++r) tmp[r] = __float2bfloat16(acc[i][j][r] + bias_v);
        *(uint2*)(vtg + ((size_t)((bb * 4 + gg) * 64 + dd)) * TT + tl) = *(const uint2*)tmp;
      }
    } else {
#pragma unroll
      for (int i = 0; i < 2; ++i) {
        const int gmb = m0 + wm + i * 16 + quad * 4;
#pragma unroll
        for (int r = 0; r < 4; ++r)
          C[(size_t)(gmb + r) * QKVD + gn] = __float2bfloat16(acc[i][j][r] + bias_v);
      }
    }
  }
}

// ---------------- gemm2: output projection, 64x128 tile, BK=64, single-buffer ------
// [4096 x 1024] * [1024 x 1024]^T-packed -> fp32 out. grid (8, 64) = 512 blocks.

__global__ __launch_bounds__(256, 4) void k_gemm2(const __hip_bfloat16* __restrict__ A,
                                                  const __hip_bfloat16* __restrict__ BT,
                                                  const float* __restrict__ bias,
                                                  float* __restrict__ C) {
  __shared__ __hip_bfloat16 As[64][64];
  __shared__ __hip_bfloat16 Bs[128][64];

  const int tid  = threadIdx.x;
  const int m0   = blockIdx.y * 64;
  const int n0   = blockIdx.x * 128;
  const int w    = tid >> 6;
  const int lane = tid & 63;
  const int quad = lane >> 4;
  const int l16  = lane & 15;
  const int wm   = (w >> 1) * 32;
  const int wn   = (w & 1) * 64;

  const int dl_r = lane >> 3;
  const int dl_c = (lane & 7) ^ dl_r;

  const __hip_bfloat16* gA = A + (size_t)(m0 + w * 16 + dl_r) * 1024 + dl_c * 8;
  const __hip_bfloat16* gB = BT + (size_t)(n0 + w * 32 + dl_r) * 1024 + dl_c * 8;

  f32x4 acc[2][4] = {};

  for (int kt = 0; kt < 16; ++kt) {
    const int k0 = kt << 6;
    gload_lds16(gA + k0,                     &As[w * 16][0]);
    gload_lds16(gA + k0 + (size_t)8 * 1024,  &As[w * 16 + 8][0]);
    gload_lds16(gB + k0,                     &Bs[w * 32][0]);
    gload_lds16(gB + k0 + (size_t)8 * 1024,  &Bs[w * 32 + 8][0]);
    gload_lds16(gB + k0 + (size_t)16 * 1024, &Bs[w * 32 + 16][0]);
    gload_lds16(gB + k0 + (size_t)24 * 1024, &Bs[w * 32 + 24][0]);
    __syncthreads();

#pragma unroll
    for (int ks = 0; ks < 2; ++ks) {
      const int cb = (ks << 2) + quad;
      bf16x8 fa[2], fb[4];
#pragma unroll
      for (int i = 0; i < 2; ++i)
        fa[i] = *(const bf16x8*)&As[wm + i * 16 + l16][(cb ^ (l16 & 7)) << 3];
#pragma unroll
      for (int j = 0; j < 4; ++j)
        fb[j] = *(const bf16x8*)&Bs[wn + j * 16 + l16][(cb ^ (l16 & 7)) << 3];
#pragma unroll
      for (int i = 0; i < 2; ++i)
#pragma unroll
        for (int j = 0; j < 4; ++j)
          acc[i][j] = __builtin_amdgcn_mfma_f32_16x16x32_bf16(fa[i], fb[j], acc[i][j], 0, 0, 0);
    }
    __syncthreads();
  }

#pragma unroll
  for (int j = 0; j < 4; ++j) {
    const int gn = n0 + wn + j * 16 + l16;
    const float bias_v = bias[gn];
#pragma unroll
    for (int i = 0; i < 2; ++i) {
      const int gmb = m0 + wm + i * 16 + quad * 4;
#pragma unroll
      for (int r = 0; r < 4; ++r)
        C[(size_t)(gmb + r) * CC + gn] = acc[i][j][r] + bias_v;
    }
  }
}

// ---------------- MFMA flash attention: LDS-staged, double-buffered (v1, proven) ----
// Fixed-shift softmax + mask specialization: only diagonal chunk (c==bx) needs
// key<=i; only tail chunk (c==bx-4) needs key>=i-256; middle chunks are mask-free.
// R1 (2-wave reuse) and R2 (L2-direct) both regressed -> this structure is the
// verified local optimum for attn.

__global__ __launch_bounds__(256) void k_attn(const __hip_bfloat16* __restrict__ qkv,
                                              const __hip_bfloat16* __restrict__ vtg,
                                              __hip_bfloat16* __restrict__ y) {
  __shared__ __hip_bfloat16 Kb[2][64][64];  // [buf][key][d]   16 KB
  __shared__ __hip_bfloat16 Vb[2][64][64];  // [buf][d][key]   16 KB
  __shared__ __hip_bfloat16 Ps[4][16][72];  // per-wave P tile 9.2 KB

  const int t    = threadIdx.x;
  const int w    = t >> 6;
  const int lane = t & 63;
  const int quad = lane >> 4;
  const int l16  = lane & 15;
  const int bx   = blockIdx.x;
  const int h    = blockIdx.y;
  const int b    = blockIdx.z;
  const int g    = h >> 2;  // repeat_interleave: heads 4g..4g+3 -> group g
  const int i0   = bx * 64;
  const int qrow      = i0 + w * 16 + l16;
  const int my_q_base = i0 + w * 16 + quad * 4;

  const int lrow = lane >> 3;
  const int cgl  = (lane & 7) ^ lrow;

  const __hip_bfloat16* kg =
      qkv + ((size_t)(b * TT + w * 16 + lrow)) * QKVD + 1024 + g * 64 + cgl * 8;
  const __hip_bfloat16* vg =
      vtg + ((size_t)((b * 4 + g) * 64 + w * 16 + lrow)) * TT + cgl * 8;

  bf16x8 fq[2];
  {
    const __hip_bfloat16* qp = qkv + ((size_t)(b * TT + qrow)) * QKVD + h * 64 + quad * 8;
    fq[0] = *(const bf16x8*)qp;
    fq[1] = *(const bf16x8*)(qp + 32);
  }

  float l_r[4] = {0.f, 0.f, 0.f, 0.f};
  f32x4 o_acc[4] = {};
  const float EC = 0.125f * 1.44269504f;  // (1/sqrt(64)) * log2(e)

  const int c_lo = bx >= 4 ? bx - 4 : 0;

  {
    const size_t ko = (size_t)(c_lo * 64) * QKVD;
    gload_lds16(kg + ko,                    &Kb[0][w * 16][0]);
    gload_lds16(kg + ko + (size_t)8 * QKVD, &Kb[0][w * 16 + 8][0]);
    const int vo = c_lo * 64;
    gload_lds16(vg + vo,                  &Vb[0][w * 16][0]);
    gload_lds16(vg + vo + (size_t)8 * TT, &Vb[0][w * 16 + 8][0]);
  }

  int buf = 0;
  for (int c = c_lo; c <= bx; ++c) {
    __syncthreads();
    if (c < bx) {
      const size_t ko = (size_t)((c + 1) * 64) * QKVD;
      gload_lds16(kg + ko,                    &Kb[buf ^ 1][w * 16][0]);
      gload_lds16(kg + ko + (size_t)8 * QKVD, &Kb[buf ^ 1][w * 16 + 8][0]);
      const int vo = (c + 1) * 64;
      gload_lds16(vg + vo,                  &Vb[buf ^ 1][w * 16][0]);
      gload_lds16(vg + vo + (size_t)8 * TT, &Vb[buf ^ 1][w * 16 + 8][0]);
    }

    const int jc = c * 64;

    f32x4 sacc[4] = {};
#pragma unroll
    for (int ks = 0; ks < 2; ++ks) {
      const int sw = (((ks << 2) + quad) ^ (l16 & 7)) << 3;
#pragma unroll
      for (int nt = 0; nt < 4; ++nt) {
        const bf16x8 fk = *(const bf16x8*)&Kb[buf][nt * 16 + l16][sw];
        sacc[nt] = __builtin_amdgcn_mfma_f32_16x16x32_bf16(fq[ks], fk, sacc[nt], 0, 0, 0);
      }
    }

    // p = exp(s/8); mask only where needed (wave-uniform chunk classification)
    if (c == bx) {            // diagonal: key <= i
#pragma unroll
      for (int r = 0; r < 4; ++r) {
        const int gi = my_q_base + r;
#pragma unroll
        for (int nt = 0; nt < 4; ++nt) {
          const int key = jc + nt * 16 + l16;
          const float p = (key <= gi) ? exp2f(sacc[nt][r] * EC) : 0.f;
          l_r[r] += p;
          Ps[w][quad * 4 + r][nt * 16 + l16] = __float2bfloat16(p);
        }
      }
    } else if (bx >= 4 && c == c_lo) {  // window tail: key >= i - 256
#pragma unroll
      for (int r = 0; r < 4; ++r) {
        const int glo = my_q_base + r - 256;
#pragma unroll
        for (int nt = 0; nt < 4; ++nt) {
          const int key = jc + nt * 16 + l16;
          const float p = (key >= glo) ? exp2f(sacc[nt][r] * EC) : 0.f;
          l_r[r] += p;
          Ps[w][quad * 4 + r][nt * 16 + l16] = __float2bfloat16(p);
        }
      }
    } else {                  // interior: mask-free
#pragma unroll
      for (int r = 0; r < 4; ++r)
#pragma unroll
        for (int nt = 0; nt < 4; ++nt) {
          const float p = exp2f(sacc[nt][r] * EC);
          l_r[r] += p;
          Ps[w][quad * 4 + r][nt * 16 + l16] = __float2bfloat16(p);
        }
    }

    const bf16x8 fp0 = *(const bf16x8*)&Ps[w][l16][quad * 8];
    const bf16x8 fp1 = *(const bf16x8*)&Ps[w][l16][32 + quad * 8];

#pragma unroll
    for (int ks = 0; ks < 2; ++ks) {
      const int sw = (((ks << 2) + quad) ^ (l16 & 7)) << 3;
#pragma unroll
      for (int jt = 0; jt < 4; ++jt) {
        const bf16x8 fv = *(const bf16x8*)&Vb[buf][jt * 16 + l16][sw];
        o_acc[jt] = __builtin_amdgcn_mfma_f32_16x16x32_bf16(ks == 0 ? fp0 : fp1, fv,
                                                            o_acc[jt], 0, 0, 0);
      }
    }
    buf ^= 1;
  }

#pragma unroll
  for (int r = 0; r < 4; ++r) {
#pragma unroll
    for (int d = 1; d < 16; d <<= 1) l_r[r] += __shfl_xor(l_r[r], d);
    const float inv = 1.f / l_r[r];
    __hip_bfloat16* yp = y + ((size_t)(b * TT + my_q_base + r)) * CC + h * 64 + l16;
#pragma unroll
    for (int jt = 0; jt < 4; ++jt)
      yp[jt * 16] = __float2bfloat16(o_acc[jt][r] * inv);
  }
}

// ---------------- launch ----------------

extern "C" void kernel_launch(void* const* d_in, const int* in_sizes, int n_in,
                              void* d_out, int out_size, void* d_ws, size_t ws_size,
                              hipStream_t stream) {
  const float* x  = (const float*)d_in[0];
  const float* Wq = (const float*)d_in[1];
  const float* bq = (const float*)d_in[2];
  const float* Wk = (const float*)d_in[3];
  const float* bk = (const float*)d_in[4];
  const float* Wv = (const float*)d_in[5];
  const float* bv = (const float*)d_in[6];
  const float* Wo = (const float*)d_in[7];
  const float* bo = (const float*)d_in[8];
  float* out = (float*)d_out;

  char* ws = (char*)d_ws;
  const size_t M = 2 * TT;  // 4096
  __hip_bfloat16* xbf   = (__hip_bfloat16*)(ws);               // 8 MB
  __hip_bfloat16* qkv   = (__hip_bfloat16*)(ws + 8388608);     // 12 MB (V region unused)
  __hip_bfloat16* ybf   = (__hip_bfloat16*)(ws + 20971520);    // 8 MB
  __hip_bfloat16* wqkvT = (__hip_bfloat16*)(ws + 29360128);    // 3 MB
  __hip_bfloat16* woT   = (__hip_bfloat16*)(ws + 32505856);    // 2 MB
  float*          bqkv  = (float*)(ws + 34603008);             // 6 KB
  __hip_bfloat16* vtg   = (__hip_bfloat16*)(ws + 34609152);    // 2 MB

  // prep: x convert (4096) + wqkv pack (384) + wo pack (256) + bias (1)
  k_prep<<<4737, 256, 0, stream>>>(x, Wq, Wk, Wv, Wo, bq, bk, bv,
                                   xbf, wqkvT, woT, bqkv);

  // QKV projection: 128x128 tiles, 8-wave blocks, grid (12, 32)
  k_gemm1<<<dim3(QKVD / 128, M / 128), 512, 0, stream>>>(xbf, wqkvT, bqkv, qkv, vtg);

  // attention: 1024 blocks, LDS-staged double-buffered flash (v1)
  k_attn<<<dim3(TT / 64, 16, 2), 256, 0, stream>>>(qkv, vtg, ybf);

  // output projection: 64x128 tiles, grid (8, 64) -> fp32
  k_gemm2<<<dim3(CC / 128, M / 64), 256, 0, stream>>>(ybf, woT, bo, out);
}

// Round 4
// 142.476 us; speedup vs baseline: 1.1836x; 1.0181x over previous
//
#include <hip/hip_runtime.h>
#include <hip/hip_bf16.h>

// Problem constants (B=2, T=2048, C=1024, H=16, G=4, hd=64, KV=256, WINDOW=256)
#define TT 2048
#define CC 1024
#define KVD 256
#define QKVD 1536

typedef __bf16 bf16x8 __attribute__((ext_vector_type(8)));
typedef float f32x4 __attribute__((ext_vector_type(4)));

// async global->LDS, 16B per lane. LDS dest is wave-uniform base + lane*16 (HW rule).
__device__ __forceinline__ void gload_lds16(const __hip_bfloat16* g, __hip_bfloat16* l) {
  __builtin_amdgcn_global_load_lds(
      (const __attribute__((address_space(1))) unsigned int*)g,
      (__attribute__((address_space(3))) unsigned int*)l, 16, 0, 0);
}

// ---------------- merged prep: x->bf16 convert + weight packs + bias ----------------
// 1D grid: [0,4096) convert x; [4096,4480) pack wqkvT; [4480,4736) pack woT; [4736] bias.

__global__ __launch_bounds__(256) void k_prep(const float* __restrict__ x,
                                              const float* __restrict__ Wq,
                                              const float* __restrict__ Wk,
                                              const float* __restrict__ Wv,
                                              const float* __restrict__ Wo,
                                              const float* __restrict__ bq,
                                              const float* __restrict__ bk,
                                              const float* __restrict__ bv,
                                              __hip_bfloat16* __restrict__ xbf,
                                              __hip_bfloat16* __restrict__ wqkvT,
                                              __hip_bfloat16* __restrict__ woT,
                                              float* __restrict__ bqkv) {
  const int bxid = blockIdx.x;
  if (bxid < 4096) {
    size_t idx = ((size_t)bxid * 256 + threadIdx.x) * 4;
    float4 v = *(const float4*)(x + idx);
    xbf[idx + 0] = __float2bfloat16(v.x);
    xbf[idx + 1] = __float2bfloat16(v.y);
    xbf[idx + 2] = __float2bfloat16(v.z);
    xbf[idx + 3] = __float2bfloat16(v.w);
    return;
  }
  if (bxid == 4736) {
    for (int i = threadIdx.x; i < 1536; i += 256) {
      float v;
      if (i < 1024)      v = bq[i];
      else if (i < 1280) v = bk[i - 1024];
      else               v = bv[i - 1280];
      bqkv[i] = v;
    }
    return;
  }
  // weight pack via LDS tile transpose, coalesced both sides
  __shared__ float tile[64][65];
  const float* src;
  int ncols, k0, n0;
  __hip_bfloat16* dst;
  if (bxid < 4480) {
    const int idx = bxid - 4096;          // 384 tiles: 16 k x 24 n
    k0 = (idx & 15) * 64;
    n0 = (idx >> 4) * 64;
    dst = wqkvT;
    if (n0 < 1024)      { src = Wq; ncols = 1024; }
    else if (n0 < 1280) { src = Wk - 1024; ncols = 256; }
    else                { src = Wv - 1280; ncols = 256; }
  } else {
    const int idx = bxid - 4480;          // 256 tiles: 16 k x 16 n
    k0 = (idx & 15) * 64;
    n0 = (idx >> 4) * 64;
    dst = woT; src = Wo; ncols = 1024;
  }
  const int rw = threadIdx.x >> 6;
  const int cl = threadIdx.x & 63;
#pragma unroll
  for (int i = 0; i < 16; ++i) {
    const int kr = rw + i * 4;
    tile[kr][cl] = src[(size_t)(k0 + kr) * ncols + n0 + cl];
  }
  __syncthreads();
#pragma unroll
  for (int i = 0; i < 16; ++i) {
    const int nr = rw + i * 4;
    dst[(size_t)(n0 + nr) * 1024 + k0 + cl] = __float2bfloat16(tile[cl][nr]);
  }
}

// ---------------- gemm1: QKV projection, 128x128 tile, BK=64, 8 waves -------------
// [4096 x 1024] * [1024 x 1536]^T-packed. 512-thread blocks (8 waves, wave-tile
// 32x64). Proven equal to the 4-wave variant (R3 == R0); kept as current form.
// V columns (n>=1280) -> vtg transposed. grid (1536/128, 4096/128) = (12, 32).

__global__ __launch_bounds__(512, 4) void k_gemm1(const __hip_bfloat16* __restrict__ A,
                                                  const __hip_bfloat16* __restrict__ BT,
                                                  const float* __restrict__ bias,
                                                  __hip_bfloat16* __restrict__ C,
                                                  __hip_bfloat16* __restrict__ vtg) {
  __shared__ __hip_bfloat16 As[128][64];   // 16 KB
  __shared__ __hip_bfloat16 Bs[128][64];   // 16 KB

  const int tid  = threadIdx.x;
  const int m0   = blockIdx.y * 128;
  const int n0   = blockIdx.x * 128;
  const int w    = tid >> 6;               // 0..7
  const int lane = tid & 63;
  const int quad = lane >> 4;
  const int l16  = lane & 15;
  const int wm   = (w & 3) * 32;           // 4 row-groups of 32
  const int wn   = (w >> 2) * 64;          // 2 col-groups of 64

  const int dl_r = lane >> 3;               // 0..7
  const int dl_c = (lane & 7) ^ dl_r;       // swizzled global 16B chunk

  // wave w stages A rows [w*16, w*16+16) and B rows [w*16, w*16+16)
  const __hip_bfloat16* gA = A + (size_t)(m0 + w * 16 + dl_r) * 1024 + dl_c * 8;
  const __hip_bfloat16* gB = BT + (size_t)(n0 + w * 16 + dl_r) * 1024 + dl_c * 8;

  f32x4 acc[2][4] = {};

  for (int kt = 0; kt < 16; ++kt) {
    const int k0 = kt << 6;
    gload_lds16(gA + k0,                    &As[w * 16][0]);
    gload_lds16(gA + k0 + (size_t)8 * 1024, &As[w * 16 + 8][0]);
    gload_lds16(gB + k0,                    &Bs[w * 16][0]);
    gload_lds16(gB + k0 + (size_t)8 * 1024, &Bs[w * 16 + 8][0]);
    __syncthreads();  // drain DMA

#pragma unroll
    for (int ks = 0; ks < 2; ++ks) {
      const int cb = (ks << 2) + quad;
      bf16x8 fa[2], fb[4];
#pragma unroll
      for (int i = 0; i < 2; ++i)
        fa[i] = *(const bf16x8*)&As[wm + i * 16 + l16][(cb ^ (l16 & 7)) << 3];
#pragma unroll
      for (int j = 0; j < 4; ++j)
        fb[j] = *(const bf16x8*)&Bs[wn + j * 16 + l16][(cb ^ (l16 & 7)) << 3];
#pragma unroll
      for (int i = 0; i < 2; ++i)
#pragma unroll
        for (int j = 0; j < 4; ++j)
          acc[i][j] = __builtin_amdgcn_mfma_f32_16x16x32_bf16(fa[i], fb[j], acc[i][j], 0, 0, 0);
    }
    __syncthreads();  // all reads done before next overwrite
  }

  // epilogue: C/D layout col=lane&15, row=quad*4+reg. 1280 boundary is wave-uniform.
#pragma unroll
  for (int j = 0; j < 4; ++j) {
    const int gn = n0 + wn + j * 16 + l16;
    const float bias_v = bias[gn];
    if (gn >= 1280) {
      // V column: write transposed into vtg[(b*4+g)*64 + d][t]
      const int dfull = gn - 1280;
      const int gg = dfull >> 6;
      const int dd = dfull & 63;
#pragma unroll
      for (int i = 0; i < 2; ++i) {
        const int gm = m0 + wm + i * 16 + quad * 4;  // 4 consecutive tokens
        const int bb = gm >> 11;
        const int tl = gm & 2047;
        __hip_bfloat16 tmp[4];
#pragma unroll
        for (int r = 0; r < 4; ++r) tmp[r] = __float2bfloat16(acc[i][j][r] + bias_v);
        *(uint2*)(vtg + ((size_t)((bb * 4 + gg) * 64 + dd)) * TT + tl) = *(const uint2*)tmp;
      }
    } else {
#pragma unroll
      for (int i = 0; i < 2; ++i) {
        const int gmb = m0 + wm + i * 16 + quad * 4;
#pragma unroll
        for (int r = 0; r < 4; ++r)
          C[(size_t)(gmb + r) * QKVD + gn] = __float2bfloat16(acc[i][j][r] + bias_v);
      }
    }
  }
}

// ---------------- gemm2: output projection, 64x128 tile, BK=64, single-buffer ------
// [4096 x 1024] * [1024 x 1024]^T-packed -> fp32 out. grid (8, 64) = 512 blocks.

__global__ __launch_bounds__(256, 4) void k_gemm2(const __hip_bfloat16* __restrict__ A,
                                                  const __hip_bfloat16* __restrict__ BT,
                                                  const float* __restrict__ bias,
                                                  float* __restrict__ C) {
  __shared__ __hip_bfloat16 As[64][64];
  __shared__ __hip_bfloat16 Bs[128][64];

  const int tid  = threadIdx.x;
  const int m0   = blockIdx.y * 64;
  const int n0   = blockIdx.x * 128;
  const int w    = tid >> 6;
  const int lane = tid & 63;
  const int quad = lane >> 4;
  const int l16  = lane & 15;
  const int wm   = (w >> 1) * 32;
  const int wn   = (w & 1) * 64;

  const int dl_r = lane >> 3;
  const int dl_c = (lane & 7) ^ dl_r;

  const __hip_bfloat16* gA = A + (size_t)(m0 + w * 16 + dl_r) * 1024 + dl_c * 8;
  const __hip_bfloat16* gB = BT + (size_t)(n0 + w * 32 + dl_r) * 1024 + dl_c * 8;

  f32x4 acc[2][4] = {};

  for (int kt = 0; kt < 16; ++kt) {
    const int k0 = kt << 6;
    gload_lds16(gA + k0,                     &As[w * 16][0]);
    gload_lds16(gA + k0 + (size_t)8 * 1024,  &As[w * 16 + 8][0]);
    gload_lds16(gB + k0,                     &Bs[w * 32][0]);
    gload_lds16(gB + k0 + (size_t)8 * 1024,  &Bs[w * 32 + 8][0]);
    gload_lds16(gB + k0 + (size_t)16 * 1024, &Bs[w * 32 + 16][0]);
    gload_lds16(gB + k0 + (size_t)24 * 1024, &Bs[w * 32 + 24][0]);
    __syncthreads();

#pragma unroll
    for (int ks = 0; ks < 2; ++ks) {
      const int cb = (ks << 2) + quad;
      bf16x8 fa[2], fb[4];
#pragma unroll
      for (int i = 0; i < 2; ++i)
        fa[i] = *(const bf16x8*)&As[wm + i * 16 + l16][(cb ^ (l16 & 7)) << 3];
#pragma unroll
      for (int j = 0; j < 4; ++j)
        fb[j] = *(const bf16x8*)&Bs[wn + j * 16 + l16][(cb ^ (l16 & 7)) << 3];
#pragma unroll
      for (int i = 0; i < 2; ++i)
#pragma unroll
        for (int j = 0; j < 4; ++j)
          acc[i][j] = __builtin_amdgcn_mfma_f32_16x16x32_bf16(fa[i], fb[j], acc[i][j], 0, 0, 0);
    }
    __syncthreads();
  }

#pragma unroll
  for (int j = 0; j < 4; ++j) {
    const int gn = n0 + wn + j * 16 + l16;
    const float bias_v = bias[gn];
#pragma unroll
    for (int i = 0; i < 2; ++i) {
      const int gmb = m0 + wm + i * 16 + quad * 4;
#pragma unroll
      for (int r = 0; r < 4; ++r)
        C[(size_t)(gmb + r) * CC + gn] = acc[i][j][r] + bias_v;
    }
  }
}

// ---------------- MFMA flash attention v4: QBLK=128, 8 waves, 2x K/V reuse --------
// R1's reuse idea done right: one K/V staging pass serves 128 q-rows (vs 64) while
// occupancy RISES (50 KB LDS -> 2-3 blocks/CU, 16+ waves/CU vs v1's 12; grid 512
// blocks = 2/CU fully resident, no tail round). Block stages 6 key-chunks
// jc = i0-256 .. i0+64; wave-group wg = w>>2 is active for cc in [wg, 4+wg]
// (5 of 6 chunks), diagonal mask at cc==4+wg, window-tail mask at cc==wg.
// Small-bx clamp: cc_lo = max(0, 4-2*bx); clamped blocks never hit a tail chunk.

__global__ __launch_bounds__(512) void k_attn(const __hip_bfloat16* __restrict__ qkv,
                                              const __hip_bfloat16* __restrict__ vtg,
                                              __hip_bfloat16* __restrict__ y) {
  __shared__ __hip_bfloat16 Kb[2][64][64];  // [buf][key][d]   16 KB
  __shared__ __hip_bfloat16 Vb[2][64][64];  // [buf][d][key]   16 KB
  __shared__ __hip_bfloat16 Ps[8][16][72];  // per-wave P tile 18.4 KB

  const int t    = threadIdx.x;
  const int w    = t >> 6;      // 0..7
  const int lane = t & 63;
  const int quad = lane >> 4;
  const int l16  = lane & 15;
  const int bx   = blockIdx.x;  // 0..15
  const int h    = blockIdx.y;
  const int b    = blockIdx.z;
  const int g    = h >> 2;      // repeat_interleave: heads 4g..4g+3 -> group g
  const int i0   = bx * 128;
  const int wg   = w >> 2;      // wave-group: 0 = rows [i0,i0+64), 1 = [i0+64,i0+128)
  const int myq0 = i0 + w * 16;
  const int qrow      = myq0 + l16;
  const int my_q_base = myq0 + quad * 4;

  const int lrow = lane >> 3;
  const int cgl  = (lane & 7) ^ lrow;

  // wave w stages rows w*8 .. w*8+7 of each 64-row K/V chunk (1 gload each)
  const __hip_bfloat16* kg =
      qkv + ((size_t)(b * TT + w * 8 + lrow)) * QKVD + 1024 + g * 64 + cgl * 8;
  const __hip_bfloat16* vg =
      vtg + ((size_t)((b * 4 + g) * 64 + w * 8 + lrow)) * TT + cgl * 8;

  bf16x8 fq[2];
  {
    const __hip_bfloat16* qp = qkv + ((size_t)(b * TT + qrow)) * QKVD + h * 64 + quad * 8;
    fq[0] = *(const bf16x8*)qp;
    fq[1] = *(const bf16x8*)(qp + 32);
  }

  float l_r[4] = {0.f, 0.f, 0.f, 0.f};
  f32x4 o_acc[4] = {};
  const float EC = 0.125f * 1.44269504f;  // (1/sqrt(64)) * log2(e)

  const int cc_lo = bx >= 2 ? 0 : (4 - 2 * bx);
  const int jbase = i0 - 256;

  {
    const int jc = jbase + cc_lo * 64;
    gload_lds16(kg + (size_t)jc * QKVD, &Kb[0][w * 8][0]);
    gload_lds16(vg + jc,                &Vb[0][w * 8][0]);
  }

  int buf = 0;
  for (int cc = cc_lo; cc < 6; ++cc) {
    __syncthreads();
    if (cc < 5) {
      const int jn = jbase + (cc + 1) * 64;
      gload_lds16(kg + (size_t)jn * QKVD, &Kb[buf ^ 1][w * 8][0]);
      gload_lds16(vg + jn,                &Vb[buf ^ 1][w * 8][0]);
    }

    if (cc >= wg && cc <= 4 + wg) {   // this wave-group's 5-chunk window
      const int jc = jbase + cc * 64;

      f32x4 sacc[4] = {};
#pragma unroll
      for (int ks = 0; ks < 2; ++ks) {
        const int sw = (((ks << 2) + quad) ^ (l16 & 7)) << 3;
#pragma unroll
        for (int nt = 0; nt < 4; ++nt) {
          const bf16x8 fk = *(const bf16x8*)&Kb[buf][nt * 16 + l16][sw];
          sacc[nt] = __builtin_amdgcn_mfma_f32_16x16x32_bf16(fq[ks], fk, sacc[nt], 0, 0, 0);
        }
      }

      // p = exp(s/8); mask only where needed (wave-uniform chunk classification)
      if (cc == 4 + wg) {        // diagonal: key <= i
#pragma unroll
        for (int r = 0; r < 4; ++r) {
          const int gi = my_q_base + r;
#pragma unroll
          for (int nt = 0; nt < 4; ++nt) {
            const int key = jc + nt * 16 + l16;
            const float p = (key <= gi) ? exp2f(sacc[nt][r] * EC) : 0.f;
            l_r[r] += p;
            Ps[w][quad * 4 + r][nt * 16 + l16] = __float2bfloat16(p);
          }
        }
      } else if (cc == wg) {     // window tail: key >= i - 256 (only reachable when jc>=0)
#pragma unroll
        for (int r = 0; r < 4; ++r) {
          const int glo = my_q_base + r - 256;
#pragma unroll
          for (int nt = 0; nt < 4; ++nt) {
            const int key = jc + nt * 16 + l16;
            const float p = (key >= glo) ? exp2f(sacc[nt][r] * EC) : 0.f;
            l_r[r] += p;
            Ps[w][quad * 4 + r][nt * 16 + l16] = __float2bfloat16(p);
          }
        }
      } else {                   // interior: mask-free
#pragma unroll
        for (int r = 0; r < 4; ++r)
#pragma unroll
          for (int nt = 0; nt < 4; ++nt) {
            const float p = exp2f(sacc[nt][r] * EC);
            l_r[r] += p;
            Ps[w][quad * 4 + r][nt * 16 + l16] = __float2bfloat16(p);
          }
      }

      const bf16x8 fp0 = *(const bf16x8*)&Ps[w][l16][quad * 8];
      const bf16x8 fp1 = *(const bf16x8*)&Ps[w][l16][32 + quad * 8];

#pragma unroll
      for (int ks = 0; ks < 2; ++ks) {
        const int sw = (((ks << 2) + quad) ^ (l16 & 7)) << 3;
#pragma unroll
        for (int jt = 0; jt < 4; ++jt) {
          const bf16x8 fv = *(const bf16x8*)&Vb[buf][jt * 16 + l16][sw];
          o_acc[jt] = __builtin_amdgcn_mfma_f32_16x16x32_bf16(ks == 0 ? fp0 : fp1, fv,
                                                              o_acc[jt], 0, 0, 0);
        }
      }
    }
    buf ^= 1;
  }

#pragma unroll
  for (int r = 0; r < 4; ++r) {
#pragma unroll
    for (int d = 1; d < 16; d <<= 1) l_r[r] += __shfl_xor(l_r[r], d);
    const float inv = 1.f / l_r[r];
    __hip_bfloat16* yp = y + ((size_t)(b * TT + my_q_base + r)) * CC + h * 64 + l16;
#pragma unroll
    for (int jt = 0; jt < 4; ++jt)
      yp[jt * 16] = __float2bfloat16(o_acc[jt][r] * inv);
  }
}

// ---------------- launch ----------------

extern "C" void kernel_launch(void* const* d_in, const int* in_sizes, int n_in,
                              void* d_out, int out_size, void* d_ws, size_t ws_size,
                              hipStream_t stream) {
  const float* x  = (const float*)d_in[0];
  const float* Wq = (const float*)d_in[1];
  const float* bq = (const float*)d_in[2];
  const float* Wk = (const float*)d_in[3];
  const float* bk = (const float*)d_in[4];
  const float* Wv = (const float*)d_in[5];
  const float* bv = (const float*)d_in[6];
  const float* Wo = (const float*)d_in[7];
  const float* bo = (const float*)d_in[8];
  float* out = (float*)d_out;

  char* ws = (char*)d_ws;
  const size_t M = 2 * TT;  // 4096
  __hip_bfloat16* xbf   = (__hip_bfloat16*)(ws);               // 8 MB
  __hip_bfloat16* qkv   = (__hip_bfloat16*)(ws + 8388608);     // 12 MB (V region unused)
  __hip_bfloat16* ybf   = (__hip_bfloat16*)(ws + 20971520);    // 8 MB
  __hip_bfloat16* wqkvT = (__hip_bfloat16*)(ws + 29360128);    // 3 MB
  __hip_bfloat16* woT   = (__hip_bfloat16*)(ws + 32505856);    // 2 MB
  float*          bqkv  = (float*)(ws + 34603008);             // 6 KB
  __hip_bfloat16* vtg   = (__hip_bfloat16*)(ws + 34609152);    // 2 MB

  // prep: x convert (4096) + wqkv pack (384) + wo pack (256) + bias (1)
  k_prep<<<4737, 256, 0, stream>>>(x, Wq, Wk, Wv, Wo, bq, bk, bv,
                                   xbf, wqkvT, woT, bqkv);

  // QKV projection: 128x128 tiles, 8-wave blocks, grid (12, 32)
  k_gemm1<<<dim3(QKVD / 128, M / 128), 512, 0, stream>>>(xbf, wqkvT, bqkv, qkv, vtg);

  // attention: 512 blocks of 512 threads (8 waves, QBLK=128)
  k_attn<<<dim3(TT / 128, 16, 2), 512, 0, stream>>>(qkv, vtg, ybf);

  // output projection: 64x128 tiles, grid (8, 64) -> fp32
  k_gemm2<<<dim3(CC / 128, M / 64), 256, 0, stream>>>(ybf, woT, bo, out);
}